// Round 1
// 506.733 us; speedup vs baseline: 1.0954x; 1.0954x over previous
//
#include <hip/hip_runtime.h>
#include <cstdint>
#include <cstddef>

// FeedForward: GroupNorm(8) -> conv1x1 C->2C -> GELU(exact) -> conv1x1 2C->C -> +x
// B=16, C=512, L=4096. ALL I/O FP32. Internal: bf16 MFMA, fp32 accum.
//
// R5 changes vs R4 (passing, 555us):
//  - gemm epilogues were VALU-bound (gemm1: MfmaUtil 14.5%, VALUBusy 56%):
//    64 libm erff/thread + 64 scalar 2B stores. Replaced erff with branchless
//    A&S 7.1.26 erf (|err|<=1.5e-7, ~14 inst via v_rcp+v_exp).
//  - MFMA operand swap (mfma(bb,af)): reg dim of C/D fragment now indexes 4
//    consecutive n per lane -> ushort4 stores of h1T (gemm1), float4 x-loads +
//    float4 out-stores (gemm2). 4x fewer epilogue VMEM ops, better L2 write
//    merging (WRITE_SIZE was 240MB vs 134MB ideal).

typedef unsigned short u16;
typedef unsigned int u32;
typedef __attribute__((ext_vector_type(8))) __bf16 bf16x8;
typedef __attribute__((ext_vector_type(4))) float floatx4;

#define BM 128
#define BN 128
#define BKK 64

__device__ __forceinline__ u16 f2bf(float f) {
    union { float f; u32 u; } v; v.f = f;
    u32 u = v.u;
    return (u16)((u + 0x7fffu + ((u >> 16) & 1u)) >> 16);  // RNE
}

// GELU(v) = 0.5 v (1 + erf(v/sqrt(2))); erf via A&S 7.1.26, |err| <= 1.5e-7.
// Branchless, ~14 VALU inst (vs ~50 for divergent libm erff).
__device__ __forceinline__ float gelu_exact(float v) {
    const float x = fabsf(v) * 0.70710678118654752f;
    const float t = __builtin_amdgcn_rcpf(fmaf(0.3275911f, x, 1.0f));
    float p = fmaf(1.061405429f, t, -1.453152027f);
    p = fmaf(p, t, 1.421413741f);
    p = fmaf(p, t, -0.284496736f);
    p = fmaf(p, t, 0.254829592f);
    p = p * t;
    const float e = __expf(-x * x);            // v_exp_f32
    const float er = fmaf(-p, e, 1.0f);        // erf(|x|)
    const float s = copysignf(er, v);          // sign restore
    return 0.5f * v * (1.0f + s);
}

__device__ __forceinline__ void async_cp16(u16* lds, const u16* g) {
    __builtin_amdgcn_global_load_lds(
        (const __attribute__((address_space(1))) u32*)g,
        (__attribute__((address_space(3))) u32*)lds,
        16, 0, 0);
}

// ---------------- kernel 1: partial group stats ----------------
__global__ __launch_bounds__(256) void gn_stats_partial(const float* __restrict__ x,
                                                        float* __restrict__ pstats) {
    const int bx = blockIdx.x;  // bg*8 + slice
    const float4* p = (const float4*)(x + (size_t)(bx >> 3) * 262144 + (size_t)(bx & 7) * 32768);
    float s = 0.f, ss = 0.f;
    for (int i = threadIdx.x; i < 8192; i += 256) {
        float4 v = p[i];
        s += v.x + v.y + v.z + v.w;
        ss += v.x * v.x + v.y * v.y + v.z * v.z + v.w * v.w;
    }
#pragma unroll
    for (int off = 32; off > 0; off >>= 1) {
        s  += __shfl_down(s, off, 64);
        ss += __shfl_down(ss, off, 64);
    }
    __shared__ float rs[8];
    const int wv = threadIdx.x >> 6;
    if ((threadIdx.x & 63) == 0) { rs[wv * 2] = s; rs[wv * 2 + 1] = ss; }
    __syncthreads();
    if (threadIdx.x == 0) {
        pstats[bx * 2]     = rs[0] + rs[2] + rs[4] + rs[6];
        pstats[bx * 2 + 1] = rs[1] + rs[3] + rs[5] + rs[7];
    }
}

// ---------------- kernel 2: weights fp32 -> bf16 ----------------
__global__ __launch_bounds__(256) void conv_w(const float* __restrict__ w1,
                                              const float* __restrict__ w2,
                                              u16* __restrict__ wb) {
    const int idx = (blockIdx.x * 256 + threadIdx.x) * 4;  // < 1048576
    const float4 v = (idx < 524288) ? *(const float4*)(w1 + idx)
                                    : *(const float4*)(w2 + (idx - 524288));
    ushort4 o;
    o.x = f2bf(v.x); o.y = f2bf(v.y); o.z = f2bf(v.z); o.w = f2bf(v.w);
    *(ushort4*)(wb + idx) = o;
}

// ---------------- kernel 3: normalize + transpose (fp32 -> bf16) ----------------
__global__ __launch_bounds__(256) void gn_norm_tr(const float* __restrict__ x,
                                                  const float* __restrict__ gamma,
                                                  const float* __restrict__ beta,
                                                  const float* __restrict__ pstats,
                                                  u16* __restrict__ xnT, int b0) {
    __shared__ u16 T[64][72];  // [l][c], c-groups XOR-swizzled by (l>>3)&7
    const int bx = blockIdx.x;
    const int lt = bx & 63, ct = (bx >> 6) & 7, bl = bx >> 9;
    const int b = b0 + bl;
    const int c0 = ct * 64, l0 = lt * 64;
    const int g = c0 >> 6;   // tile spans exactly one group
    float S = 0.f, SS = 0.f;
#pragma unroll
    for (int s2 = 0; s2 < 8; ++s2) {
        S  += pstats[((b * 8 + g) * 8 + s2) * 2];
        SS += pstats[((b * 8 + g) * 8 + s2) * 2 + 1];
    }
    const float inv = 1.f / 262144.f;
    const float mean = S * inv;
    const float var = SS * inv - mean * mean;  // population var (jnp.var)
    const float rstd = rsqrtf(var + 1e-5f);

    const int t = threadIdx.x;
    const int cl = t >> 3;          // 0..31
    const int lo = (t & 7) * 8;     // 8 l's per thread
    const int sw = t & 7;           // == (l>>3)&7 for this thread's l's
#pragma unroll
    for (int h = 0; h < 2; ++h) {
        const int c = c0 + cl + h * 32;
        const float sc = rstd * gamma[c];
        const float sh = beta[c] - mean * sc;
        const float* src = x + ((size_t)(b * 512 + c) * 4096 + l0 + lo);
        float4 a = *(const float4*)src;
        float4 bq = *(const float4*)(src + 4);
        float vv[8] = {a.x, a.y, a.z, a.w, bq.x, bq.y, bq.z, bq.w};
        const int ccol = cl + h * 32;
        const int cg = ccol >> 3, cr = ccol & 7;
#pragma unroll
        for (int q = 0; q < 8; ++q)
            T[lo + q][((cg ^ sw) << 3) + cr] = f2bf(fmaf(vv[q], sc, sh));
    }
    __syncthreads();
    const int ll = t >> 3;
    const int co = (t & 7) * 8, cog = t & 7;
#pragma unroll
    for (int h = 0; h < 2; ++h) {
        const int l = ll + h * 32;
        const uint4* srcv = (const uint4*)&T[l][(cog ^ ((l >> 3) & 7)) << 3];
        *(uint4*)(xnT + ((size_t)(bl * 4096 + l0 + l) * 512 + c0 + co)) = *srcv;
    }
}

// ---------------- GEMM core (gemm_bt): C[m][n] = sum_k A[m][k]*B[n][k] ----------------
// Staging: global_load_lds width=16. LDS slot idx holds global k-group
// (idx&7)^(row&7)  (XOR baked into the GLOBAL fetch address; LDS lane-linear).
// Read for (row, kgroup g) -> slot col g^(row&7); row&7 == fr&7 here.
// MFMA operand order is SWAPPED (bb first): C/D fragment maps
//   col = lane&15  -> m (af rows),  row = quad*4+reg -> n (bb rows)
// so each lane's 4 acc regs are CONSECUTIVE n -> vectorized epilogue stores.
__device__ __forceinline__ void gemm_core(const u16* __restrict__ Ag,  // [*][K] bf16
                                          const u16* __restrict__ Bg,  // [*][K] bf16
                                          int K, floatx4 acc[4][4],
                                          u16* lA, u16* lB,
                                          int wm, int wn, int fr, int quad) {
    const int t = threadIdx.x;
    for (int kt = 0; kt < K; kt += BKK) {
#pragma unroll
        for (int s = 0; s < 4; ++s) {
            int idx = s * 256 + t;
            int row = idx >> 3;
            int kg = (idx & 7) ^ (row & 7);
            async_cp16(lA + idx * 8, Ag + (size_t)row * K + kt + kg * 8);
        }
#pragma unroll
        for (int s = 0; s < 4; ++s) {
            int idx = s * 256 + t;
            int row = idx >> 3;
            int kg = (idx & 7) ^ (row & 7);
            async_cp16(lB + idx * 8, Bg + (size_t)row * K + kt + kg * 8);
        }
        __syncthreads();  // vmcnt(0) drain before s_barrier (compiler-emitted)
#pragma unroll
        for (int kk = 0; kk < BKK; kk += 32) {
            bf16x8 af[4], bb[4];
#pragma unroll
            for (int i = 0; i < 4; ++i) {
                int row = wm + i * 16 + fr;
                int kg = ((kk >> 3) + quad) ^ (fr & 7);
                af[i] = *(const bf16x8*)(lA + row * BKK + kg * 8);
            }
#pragma unroll
            for (int j = 0; j < 4; ++j) {
                int row = wn + j * 16 + fr;
                int kg = ((kk >> 3) + quad) ^ (fr & 7);
                bb[j] = *(const bf16x8*)(lB + row * BKK + kg * 8);
            }
#pragma unroll
            for (int i = 0; i < 4; ++i)
#pragma unroll
                for (int j = 0; j < 4; ++j)
                    acc[i][j] = __builtin_amdgcn_mfma_f32_16x16x32_bf16(bb[j], af[i], acc[i][j], 0, 0, 0);
        }
        __syncthreads();
    }
}

// ---------------- kernel 4: GEMM1 + bias + exact GELU -> h1T (bf16) ----------------
__global__ __launch_bounds__(256) void gemm1(const u16* __restrict__ xnT,
                                             const u16* __restrict__ w1b,
                                             const float* __restrict__ b1,
                                             u16* __restrict__ h1T) {
    __shared__ uint4 lAq[BM * BKK / 8], lBq[BN * BKK / 8];
    u16* lA = (u16*)lAq; u16* lB = (u16*)lBq;
    const int bx = blockIdx.x;
    // XCD swizzle: mt%8 == bx%8, the 8 nt's of one mt adjacent in dispatch.
    const int nt = (bx >> 3) & 7;
    const int mt = (bx & 7) | ((bx >> 6) << 3);
    const int t = threadIdx.x, lane = t & 63, wv = t >> 6;
    const int wm = (wv & 1) * 64, wn = (wv >> 1) * 64;
    const int fr = lane & 15, quad = lane >> 4;
    floatx4 acc[4][4];
#pragma unroll
    for (int i = 0; i < 4; ++i)
#pragma unroll
        for (int j = 0; j < 4; ++j) acc[i][j] = (floatx4){0.f, 0.f, 0.f, 0.f};

    gemm_core(xnT + (size_t)(mt * BM) * 512, w1b + (size_t)(nt * BN) * 512, 512,
              acc, lA, lB, wm, wn, fr, quad);

    // swapped layout: m <- col (fr), n <- row (quad*4 + reg)
    const int mb = mt * BM + wm + fr;
    const int nb = nt * BN + wn + quad * 4;
#pragma unroll
    for (int j = 0; j < 4; ++j) {
        const int n0 = nb + j * 16;
        const float4 bv = *(const float4*)(b1 + n0);
#pragma unroll
        for (int i = 0; i < 4; ++i) {
            const int m = mb + i * 16;
            ushort4 o;
            o.x = f2bf(gelu_exact(acc[i][j][0] + bv.x));
            o.y = f2bf(gelu_exact(acc[i][j][1] + bv.y));
            o.z = f2bf(gelu_exact(acc[i][j][2] + bv.z));
            o.w = f2bf(gelu_exact(acc[i][j][3] + bv.w));
            *(ushort4*)(h1T + (size_t)m * 1024 + n0) = o;
        }
    }
}

// ---------------- kernel 5: GEMM2 + bias + residual -> out (fp32) ----------------
__global__ __launch_bounds__(256) void gemm2(const u16* __restrict__ w2b,
                                             const u16* __restrict__ h1T,
                                             const float* __restrict__ b2,
                                             const float* __restrict__ x,
                                             float* __restrict__ out, int b0) {
    __shared__ uint4 lAq[BM * BKK / 8], lBq[BN * BKK / 8];
    u16* lA = (u16*)lAq; u16* lB = (u16*)lBq;
    const int bx = blockIdx.x;
    // XCD swizzle: nt%8 == bx%8, the 4 mt's of one nt adjacent in dispatch.
    const int mt = (bx >> 3) & 3;
    const int nt = (bx & 7) | ((bx >> 5) << 3);
    const int t = threadIdx.x, lane = t & 63, wv = t >> 6;
    const int wm = (wv & 1) * 64, wn = (wv >> 1) * 64;
    const int fr = lane & 15, quad = lane >> 4;
    floatx4 acc[4][4];
#pragma unroll
    for (int i = 0; i < 4; ++i)
#pragma unroll
        for (int j = 0; j < 4; ++j) acc[i][j] = (floatx4){0.f, 0.f, 0.f, 0.f};

    gemm_core(w2b + (size_t)(mt * BM) * 1024, h1T + (size_t)(nt * BN) * 1024, 1024,
              acc, lA, lB, wm, wn, fr, quad);

    const int n0g = b0 * 4096 + nt * BN;  // global flat (b,l); tiles never straddle b
    const int b = n0g >> 12;
    const int l_base = n0g & 4095;
    // swapped layout: m <- col (fr) = channel c, n <- row (quad*4 + reg) = l offset
    const int mb = mt * BM + wm + fr;
    const int nb = wn + quad * 4;
#pragma unroll
    for (int i = 0; i < 4; ++i) {
        const int m = mb + i * 16;
        const float bv = b2[m];
        const size_t rowoff = ((size_t)(b * 512 + m)) * 4096 + l_base + nb;
#pragma unroll
        for (int j = 0; j < 4; ++j) {
            const float4 xv = *(const float4*)(x + rowoff + j * 16);
            float4 ov;
            ov.x = acc[i][j][0] + bv + xv.x;
            ov.y = acc[i][j][1] + bv + xv.y;
            ov.z = acc[i][j][2] + bv + xv.z;
            ov.w = acc[i][j][3] + bv + xv.w;
            *(float4*)(out + rowoff + j * 16) = ov;
        }
    }
}

extern "C" void kernel_launch(void* const* d_in, const int* in_sizes, int n_in,
                              void* d_out, int out_size, void* d_ws, size_t ws_size,
                              hipStream_t stream) {
    const float* x     = (const float*)d_in[0];
    const float* gamma = (const float*)d_in[1];
    const float* beta  = (const float*)d_in[2];
    const float* w1    = (const float*)d_in[3];
    const float* b1    = (const float*)d_in[4];
    const float* w2    = (const float*)d_in[5];
    const float* b2    = (const float*)d_in[6];
    float* out = (float*)d_out;

    char* ws = (char*)d_ws;
    float* pstats = (float*)ws;                    // 8 KB used
    u16* wb = (u16*)(ws + 65536);                  // 2 MiB: w1b then w2b
    char* chunkbase = ws + 65536 + (2u << 20);
    const size_t fixed = 65536 + (2u << 20);

    // choose smallest chunk count NC so xnT+h1T fit in ws
    const size_t per = (size_t)192 * 1024 * 1024;  // NC=1: 64 MiB xnT + 128 MiB h1T
    int NC = 16;
    if      (ws_size >= fixed + per)      NC = 1;
    else if (ws_size >= fixed + per / 2)  NC = 2;
    else if (ws_size >= fixed + per / 4)  NC = 4;
    else if (ws_size >= fixed + per / 8)  NC = 8;
    const int CB = 16 / NC;                        // batches per chunk
    u16* xnT = (u16*)chunkbase;
    u16* h1T = (u16*)(chunkbase + (size_t)CB * 4096 * 512 * 2);

    gn_stats_partial<<<1024, 256, 0, stream>>>(x, pstats);
    conv_w<<<1024, 256, 0, stream>>>(w1, w2, wb);
    for (int ch = 0; ch < NC; ++ch) {
        const int b0 = ch * CB;
        gn_norm_tr<<<CB * 512, 256, 0, stream>>>(x, gamma, beta, pstats, xnT, b0);
        gemm1<<<CB * 32 * 8, 256, 0, stream>>>(xnT, wb, b1, h1T);
        gemm2<<<CB * 32 * 4, 256, 0, stream>>>(wb + 524288, h1T, b2, x, out, b0);
    }
}

// Round 2
// 481.684 us; speedup vs baseline: 1.1523x; 1.0520x over previous
//
#include <hip/hip_runtime.h>
#include <cstdint>
#include <cstddef>

// FeedForward: GroupNorm(8) -> conv1x1 C->2C -> GELU(exact) -> conv1x1 2C->C -> +x
// B=16, C=512, L=4096. ALL I/O FP32. Internal: bf16 MFMA, fp32 accum.
//
// R6 changes vs R5 (passing, 507us):
//  - gemm_core: double-buffered LDS (64KB) + prefetch-issue BEFORE compute
//    (catalog T3-minimum). Old: stage; sync(drain); compute; sync -> full
//    HBM/L3 latency exposed at every K-step drain (short K=512/1024 blocks
//    can't hide it via TLP; gemm1 per-K-step was 2.1x slower than m97@4096^3).
//    New: issue loads->buf^1; ds_read+MFMA on buf; ONE sync per step. The
//    vmcnt(0) drain at the barrier now waits loads that had the whole MFMA
//    phase to complete.
//  - R5 kept: branchless A&S erf GELU, swapped mfma(bb,af) -> vectorized
//    epilogues (ushort4 h1T stores / float4 x-loads + out-stores).

typedef unsigned short u16;
typedef unsigned int u32;
typedef __attribute__((ext_vector_type(8))) __bf16 bf16x8;
typedef __attribute__((ext_vector_type(4))) float floatx4;

#define BM 128
#define BN 128
#define BKK 64

__device__ __forceinline__ u16 f2bf(float f) {
    union { float f; u32 u; } v; v.f = f;
    u32 u = v.u;
    return (u16)((u + 0x7fffu + ((u >> 16) & 1u)) >> 16);  // RNE
}

// GELU(v) = 0.5 v (1 + erf(v/sqrt(2))); erf via A&S 7.1.26, |err| <= 1.5e-7.
__device__ __forceinline__ float gelu_exact(float v) {
    const float x = fabsf(v) * 0.70710678118654752f;
    const float t = __builtin_amdgcn_rcpf(fmaf(0.3275911f, x, 1.0f));
    float p = fmaf(1.061405429f, t, -1.453152027f);
    p = fmaf(p, t, 1.421413741f);
    p = fmaf(p, t, -0.284496736f);
    p = fmaf(p, t, 0.254829592f);
    p = p * t;
    const float e = __expf(-x * x);            // v_exp_f32
    const float er = fmaf(-p, e, 1.0f);        // erf(|x|)
    const float s = copysignf(er, v);          // sign restore
    return 0.5f * v * (1.0f + s);
}

__device__ __forceinline__ void async_cp16(u16* lds, const u16* g) {
    __builtin_amdgcn_global_load_lds(
        (const __attribute__((address_space(1))) u32*)g,
        (__attribute__((address_space(3))) u32*)lds,
        16, 0, 0);
}

// ---------------- kernel 1: partial group stats ----------------
__global__ __launch_bounds__(256) void gn_stats_partial(const float* __restrict__ x,
                                                        float* __restrict__ pstats) {
    const int bx = blockIdx.x;  // bg*8 + slice
    const float4* p = (const float4*)(x + (size_t)(bx >> 3) * 262144 + (size_t)(bx & 7) * 32768);
    float s = 0.f, ss = 0.f;
    for (int i = threadIdx.x; i < 8192; i += 256) {
        float4 v = p[i];
        s += v.x + v.y + v.z + v.w;
        ss += v.x * v.x + v.y * v.y + v.z * v.z + v.w * v.w;
    }
#pragma unroll
    for (int off = 32; off > 0; off >>= 1) {
        s  += __shfl_down(s, off, 64);
        ss += __shfl_down(ss, off, 64);
    }
    __shared__ float rs[8];
    const int wv = threadIdx.x >> 6;
    if ((threadIdx.x & 63) == 0) { rs[wv * 2] = s; rs[wv * 2 + 1] = ss; }
    __syncthreads();
    if (threadIdx.x == 0) {
        pstats[bx * 2]     = rs[0] + rs[2] + rs[4] + rs[6];
        pstats[bx * 2 + 1] = rs[1] + rs[3] + rs[5] + rs[7];
    }
}

// ---------------- kernel 2: weights fp32 -> bf16 ----------------
__global__ __launch_bounds__(256) void conv_w(const float* __restrict__ w1,
                                              const float* __restrict__ w2,
                                              u16* __restrict__ wb) {
    const int idx = (blockIdx.x * 256 + threadIdx.x) * 4;  // < 1048576
    const float4 v = (idx < 524288) ? *(const float4*)(w1 + idx)
                                    : *(const float4*)(w2 + (idx - 524288));
    ushort4 o;
    o.x = f2bf(v.x); o.y = f2bf(v.y); o.z = f2bf(v.z); o.w = f2bf(v.w);
    *(ushort4*)(wb + idx) = o;
}

// ---------------- kernel 3: normalize + transpose (fp32 -> bf16) ----------------
__global__ __launch_bounds__(256) void gn_norm_tr(const float* __restrict__ x,
                                                  const float* __restrict__ gamma,
                                                  const float* __restrict__ beta,
                                                  const float* __restrict__ pstats,
                                                  u16* __restrict__ xnT, int b0) {
    __shared__ u16 T[64][72];  // [l][c], c-groups XOR-swizzled by (l>>3)&7
    const int bx = blockIdx.x;
    const int lt = bx & 63, ct = (bx >> 6) & 7, bl = bx >> 9;
    const int b = b0 + bl;
    const int c0 = ct * 64, l0 = lt * 64;
    const int g = c0 >> 6;   // tile spans exactly one group
    float S = 0.f, SS = 0.f;
#pragma unroll
    for (int s2 = 0; s2 < 8; ++s2) {
        S  += pstats[((b * 8 + g) * 8 + s2) * 2];
        SS += pstats[((b * 8 + g) * 8 + s2) * 2 + 1];
    }
    const float inv = 1.f / 262144.f;
    const float mean = S * inv;
    const float var = SS * inv - mean * mean;  // population var (jnp.var)
    const float rstd = rsqrtf(var + 1e-5f);

    const int t = threadIdx.x;
    const int cl = t >> 3;          // 0..31
    const int lo = (t & 7) * 8;     // 8 l's per thread
    const int sw = t & 7;           // == (l>>3)&7 for this thread's l's
#pragma unroll
    for (int h = 0; h < 2; ++h) {
        const int c = c0 + cl + h * 32;
        const float sc = rstd * gamma[c];
        const float sh = beta[c] - mean * sc;
        const float* src = x + ((size_t)(b * 512 + c) * 4096 + l0 + lo);
        float4 a = *(const float4*)src;
        float4 bq = *(const float4*)(src + 4);
        float vv[8] = {a.x, a.y, a.z, a.w, bq.x, bq.y, bq.z, bq.w};
        const int ccol = cl + h * 32;
        const int cg = ccol >> 3, cr = ccol & 7;
#pragma unroll
        for (int q = 0; q < 8; ++q)
            T[lo + q][((cg ^ sw) << 3) + cr] = f2bf(fmaf(vv[q], sc, sh));
    }
    __syncthreads();
    const int ll = t >> 3;
    const int co = (t & 7) * 8, cog = t & 7;
#pragma unroll
    for (int h = 0; h < 2; ++h) {
        const int l = ll + h * 32;
        const uint4* srcv = (const uint4*)&T[l][(cog ^ ((l >> 3) & 7)) << 3];
        *(uint4*)(xnT + ((size_t)(bl * 4096 + l0 + l) * 512 + c0 + co)) = *srcv;
    }
}

// ---------------- GEMM core (gemm_bt): C[m][n] = sum_k A[m][k]*B[n][k] ----------------
// Double-buffered. Staging: global_load_lds width=16, XOR k-swizzle baked into
// the GLOBAL fetch address (LDS dest lane-linear per m104). Per K-step:
//   issue async loads -> buf^1 ; ds_read+MFMA on buf ; __syncthreads (drain+bar).
// Loads overlap the MFMA phase instead of being drained right after issue.
// MFMA operand order SWAPPED (bb first): C/D maps col=lane&15 -> m (af rows),
// row=quad*4+reg -> n (bb rows) -> lane's 4 acc regs are consecutive n.
__device__ __forceinline__ void gemm_core(const u16* __restrict__ Ag,  // [*][K] bf16
                                          const u16* __restrict__ Bg,  // [*][K] bf16
                                          int K, floatx4 acc[4][4],
                                          u16* lA, u16* lB,
                                          int wm, int wn, int fr, int quad) {
    const int t = threadIdx.x;

    auto stage = [&](int buf, int kt) {
        u16* dA = lA + buf * (BM * BKK);
        u16* dB = lB + buf * (BN * BKK);
#pragma unroll
        for (int s = 0; s < 4; ++s) {
            int idx = s * 256 + t;
            int row = idx >> 3;
            int kg = (idx & 7) ^ (row & 7);
            async_cp16(dA + idx * 8, Ag + (size_t)row * K + kt + kg * 8);
        }
#pragma unroll
        for (int s = 0; s < 4; ++s) {
            int idx = s * 256 + t;
            int row = idx >> 3;
            int kg = (idx & 7) ^ (row & 7);
            async_cp16(dB + idx * 8, Bg + (size_t)row * K + kt + kg * 8);
        }
    };

    stage(0, 0);
    __syncthreads();  // buf0 ready
    int cur = 0;
    for (int kt = 0; kt < K; kt += BKK) {
        if (kt + BKK < K) stage(cur ^ 1, kt + BKK);  // in flight across MFMA phase
        const u16* bA = lA + cur * (BM * BKK);
        const u16* bB = lB + cur * (BN * BKK);
#pragma unroll
        for (int kk = 0; kk < BKK; kk += 32) {
            bf16x8 af[4], bb[4];
#pragma unroll
            for (int i = 0; i < 4; ++i) {
                int row = wm + i * 16 + fr;
                int kg = ((kk >> 3) + quad) ^ (fr & 7);
                af[i] = *(const bf16x8*)(bA + row * BKK + kg * 8);
            }
#pragma unroll
            for (int j = 0; j < 4; ++j) {
                int row = wn + j * 16 + fr;
                int kg = ((kk >> 3) + quad) ^ (fr & 7);
                bb[j] = *(const bf16x8*)(bB + row * BKK + kg * 8);
            }
#pragma unroll
            for (int i = 0; i < 4; ++i)
#pragma unroll
                for (int j = 0; j < 4; ++j)
                    acc[i][j] = __builtin_amdgcn_mfma_f32_16x16x32_bf16(bb[j], af[i], acc[i][j], 0, 0, 0);
        }
        __syncthreads();  // drains prefetch (mostly complete) + releases buf[cur]
        cur ^= 1;
    }
}

// ---------------- kernel 4: GEMM1 + bias + exact GELU -> h1T (bf16) ----------------
__global__ __launch_bounds__(256) void gemm1(const u16* __restrict__ xnT,
                                             const u16* __restrict__ w1b,
                                             const float* __restrict__ b1,
                                             u16* __restrict__ h1T) {
    __shared__ uint4 lAq[2 * BM * BKK / 8], lBq[2 * BN * BKK / 8];
    u16* lA = (u16*)lAq; u16* lB = (u16*)lBq;
    const int bx = blockIdx.x;
    // XCD swizzle: mt%8 == bx%8, the 8 nt's of one mt adjacent in dispatch.
    const int nt = (bx >> 3) & 7;
    const int mt = (bx & 7) | ((bx >> 6) << 3);
    const int t = threadIdx.x, lane = t & 63, wv = t >> 6;
    const int wm = (wv & 1) * 64, wn = (wv >> 1) * 64;
    const int fr = lane & 15, quad = lane >> 4;
    floatx4 acc[4][4];
#pragma unroll
    for (int i = 0; i < 4; ++i)
#pragma unroll
        for (int j = 0; j < 4; ++j) acc[i][j] = (floatx4){0.f, 0.f, 0.f, 0.f};

    gemm_core(xnT + (size_t)(mt * BM) * 512, w1b + (size_t)(nt * BN) * 512, 512,
              acc, lA, lB, wm, wn, fr, quad);

    // swapped layout: m <- col (fr), n <- row (quad*4 + reg)
    const int mb = mt * BM + wm + fr;
    const int nb = nt * BN + wn + quad * 4;
#pragma unroll
    for (int j = 0; j < 4; ++j) {
        const int n0 = nb + j * 16;
        const float4 bv = *(const float4*)(b1 + n0);
#pragma unroll
        for (int i = 0; i < 4; ++i) {
            const int m = mb + i * 16;
            ushort4 o;
            o.x = f2bf(gelu_exact(acc[i][j][0] + bv.x));
            o.y = f2bf(gelu_exact(acc[i][j][1] + bv.y));
            o.z = f2bf(gelu_exact(acc[i][j][2] + bv.z));
            o.w = f2bf(gelu_exact(acc[i][j][3] + bv.w));
            *(ushort4*)(h1T + (size_t)m * 1024 + n0) = o;
        }
    }
}

// ---------------- kernel 5: GEMM2 + bias + residual -> out (fp32) ----------------
__global__ __launch_bounds__(256) void gemm2(const u16* __restrict__ w2b,
                                             const u16* __restrict__ h1T,
                                             const float* __restrict__ b2,
                                             const float* __restrict__ x,
                                             float* __restrict__ out, int b0) {
    __shared__ uint4 lAq[2 * BM * BKK / 8], lBq[2 * BN * BKK / 8];
    u16* lA = (u16*)lAq; u16* lB = (u16*)lBq;
    const int bx = blockIdx.x;
    // XCD swizzle: nt%8 == bx%8, the 4 mt's of one nt adjacent in dispatch.
    const int mt = (bx >> 3) & 3;
    const int nt = (bx & 7) | ((bx >> 5) << 3);
    const int t = threadIdx.x, lane = t & 63, wv = t >> 6;
    const int wm = (wv & 1) * 64, wn = (wv >> 1) * 64;
    const int fr = lane & 15, quad = lane >> 4;
    floatx4 acc[4][4];
#pragma unroll
    for (int i = 0; i < 4; ++i)
#pragma unroll
        for (int j = 0; j < 4; ++j) acc[i][j] = (floatx4){0.f, 0.f, 0.f, 0.f};

    gemm_core(w2b + (size_t)(mt * BM) * 1024, h1T + (size_t)(nt * BN) * 1024, 1024,
              acc, lA, lB, wm, wn, fr, quad);

    const int n0g = b0 * 4096 + nt * BN;  // global flat (b,l); tiles never straddle b
    const int b = n0g >> 12;
    const int l_base = n0g & 4095;
    // swapped layout: m <- col (fr) = channel c, n <- row (quad*4 + reg) = l offset
    const int mb = mt * BM + wm + fr;
    const int nb = wn + quad * 4;
#pragma unroll
    for (int i = 0; i < 4; ++i) {
        const int m = mb + i * 16;
        const float bv = b2[m];
        const size_t rowoff = ((size_t)(b * 512 + m)) * 4096 + l_base + nb;
#pragma unroll
        for (int j = 0; j < 4; ++j) {
            const float4 xv = *(const float4*)(x + rowoff + j * 16);
            float4 ov;
            ov.x = acc[i][j][0] + bv + xv.x;
            ov.y = acc[i][j][1] + bv + xv.y;
            ov.z = acc[i][j][2] + bv + xv.z;
            ov.w = acc[i][j][3] + bv + xv.w;
            *(float4*)(out + rowoff + j * 16) = ov;
        }
    }
}

extern "C" void kernel_launch(void* const* d_in, const int* in_sizes, int n_in,
                              void* d_out, int out_size, void* d_ws, size_t ws_size,
                              hipStream_t stream) {
    const float* x     = (const float*)d_in[0];
    const float* gamma = (const float*)d_in[1];
    const float* beta  = (const float*)d_in[2];
    const float* w1    = (const float*)d_in[3];
    const float* b1    = (const float*)d_in[4];
    const float* w2    = (const float*)d_in[5];
    const float* b2    = (const float*)d_in[6];
    float* out = (float*)d_out;

    char* ws = (char*)d_ws;
    float* pstats = (float*)ws;                    // 8 KB used
    u16* wb = (u16*)(ws + 65536);                  // 2 MiB: w1b then w2b
    char* chunkbase = ws + 65536 + (2u << 20);
    const size_t fixed = 65536 + (2u << 20);

    // choose smallest chunk count NC so xnT+h1T fit in ws
    const size_t per = (size_t)192 * 1024 * 1024;  // NC=1: 64 MiB xnT + 128 MiB h1T
    int NC = 16;
    if      (ws_size >= fixed + per)      NC = 1;
    else if (ws_size >= fixed + per / 2)  NC = 2;
    else if (ws_size >= fixed + per / 4)  NC = 4;
    else if (ws_size >= fixed + per / 8)  NC = 8;
    const int CB = 16 / NC;                        // batches per chunk
    u16* xnT = (u16*)chunkbase;
    u16* h1T = (u16*)(chunkbase + (size_t)CB * 4096 * 512 * 2);

    gn_stats_partial<<<1024, 256, 0, stream>>>(x, pstats);
    conv_w<<<1024, 256, 0, stream>>>(w1, w2, wb);
    for (int ch = 0; ch < NC; ++ch) {
        const int b0 = ch * CB;
        gn_norm_tr<<<CB * 512, 256, 0, stream>>>(x, gamma, beta, pstats, xnT, b0);
        gemm1<<<CB * 32 * 8, 256, 0, stream>>>(xnT, wb, b1, h1T);
        gemm2<<<CB * 32 * 4, 256, 0, stream>>>(wb + 524288, h1T, b2, x, out, b0);
    }
}